// Round 4
// baseline (292.594 us; speedup 1.0000x reference)
//
#include <hip/hip_runtime.h>
#include <hip/hip_bf16.h>

#define BATCH   16
#define NN      1024
#define ROWS    64      // score rows per workgroup
#define NWAVES  16
#define NTHR    1024
#define BK      32      // K-slice per step
#define NSTEP   (NN / BK)
#define MT      4       // 16-row M tiles per wave
#define NCT     4       // 16-col tiles per wave -> 64 cols/wave

typedef __attribute__((ext_vector_type(8))) short short8;   // 8 x bf16
typedef __attribute__((ext_vector_type(4))) float f32x4;

static __device__ __forceinline__ unsigned short cvt_bf16(float f) {
    unsigned int u = __builtin_bit_cast(unsigned int, f);
    u += 0x7fffu + ((u >> 16) & 1u);
    return (unsigned short)(u >> 16);
}

// pre-pass: x (fp32) -> bf16 copy in workspace (also halves L2-side BW demand)
__global__ __launch_bounds__(256)
void cvt_kernel(const float* __restrict__ x, unsigned short* __restrict__ xw) {
    const int n4 = BATCH * NN * NN / 4;
    int i = blockIdx.x * 256 + threadIdx.x;
    const int stride = gridDim.x * 256;
    for (; i < n4; i += stride) {
        float4 v = reinterpret_cast<const float4*>(x)[i];
        ushort4 h;
        h.x = cvt_bf16(v.x); h.y = cvt_bf16(v.y);
        h.z = cvt_bf16(v.z); h.w = cvt_bf16(v.w);
        reinterpret_cast<ushort4*>(xw)[i] = h;
    }
}

// stage one bf16 K-slice [1024 rows x BK] into LDS buffer bb, coalesced,
// with source-granule XOR permute (read side applies the same involution)
#define STAGE(bb, k0)                                                          \
    {                                                                          \
        _Pragma("unroll")                                                      \
        for (int c = 0; c < 4; ++c) {                                          \
            __builtin_amdgcn_global_load_lds(                                  \
                (const __attribute__((address_space(1))) void*)(xwb + soff[c] + (k0)), \
                (__attribute__((address_space(3))) void*)(lds + (bb) * 65536 + (wid * 4 + c) * 1024), \
                16, 0, 0);                                                     \
        }                                                                      \
    }

__global__ __launch_bounds__(NTHR, 1)
void attn_v4(const float* __restrict__ x, const unsigned short* __restrict__ xw,
             float* __restrict__ out) {
    // batch-contiguous XCD swizzle: XCD (wg&7) hosts batches {wg&7, (wg&7)+8}
    const int wg   = blockIdx.x;
    const int t_   = wg >> 3;
    const int b    = (wg & 7) + 8 * (t_ >> 4);
    const int i0   = (t_ & 15) * ROWS;
    const int tid  = threadIdx.x;
    const int lane = tid & 63;
    const int wid  = tid >> 6;
    const int l15  = lane & 15;   // M/N index within a 16-tile
    const int g    = lane >> 4;   // K-group / C-row group

    __shared__ __align__(16) unsigned char lds[131072];   // 2 x 64 KiB slices / P-buf
    __shared__ float redbuf[NWAVES][ROWS];                // 4 KiB

    const unsigned short* xwb = xw + (size_t)b * (NN * NN);
    const float* xb = x + (size_t)b * (NN * NN);

    // per-lane staging source offsets: LDS granule G = wid*256 + c*64 + lane
    // holds global granule (row = G>>2, s = (lane&3) ^ ((row>>1)&3))
    int soff[4];
    #pragma unroll
    for (int c = 0; c < 4; ++c) {
        int G   = wid * 256 + c * 64 + lane;
        int row = G >> 2;
        int sg  = (lane & 3) ^ ((row >> 1) & 3);
        soff[c] = row * NN + sg * 8;
    }

    f32x4 acc[MT][NCT];
    #pragma unroll
    for (int r = 0; r < MT; ++r)
        #pragma unroll
        for (int ct = 0; ct < NCT; ++ct)
            acc[r][ct] = (f32x4){0.f, 0.f, 0.f, 0.f};

    const int jb = wid * (NCT * 16);   // wave's col base

    // ---- 2-phase double-buffered K-loop (T3-min) ----
    STAGE(0, 0)
    __syncthreads();

    #pragma unroll 1
    for (int t = 0; t < NSTEP; ++t) {
        if (t + 1 < NSTEP) STAGE((t + 1) & 1, (t + 1) * BK)

        const unsigned char* cur = lds + (t & 1) * 65536;
        short8 af[MT], bfr[NCT];
        #pragma unroll
        for (int r = 0; r < MT; ++r) {
            int row = i0 + r * 16 + l15;                   // A rows live in the slice too
            int gr  = row * 4 + (g ^ ((row >> 1) & 3));
            af[r] = *reinterpret_cast<const short8*>(cur + gr * 16);
        }
        #pragma unroll
        for (int ct = 0; ct < NCT; ++ct) {
            int row = jb + ct * 16 + l15;
            int gr  = row * 4 + (g ^ ((row >> 1) & 3));
            bfr[ct] = *reinterpret_cast<const short8*>(cur + gr * 16);
        }

        __builtin_amdgcn_s_setprio(1);
        #pragma unroll
        for (int r = 0; r < MT; ++r)
            #pragma unroll
            for (int ct = 0; ct < NCT; ++ct)
                acc[r][ct] = __builtin_amdgcn_mfma_f32_16x16x32_bf16(
                    af[r], bfr[ct], acc[r][ct], 0, 0, 0);
        __builtin_amdgcn_s_setprio(0);

        __syncthreads();   // drains vmcnt (stage) + lgkm; publishes next slice
    }

    // ---- softmax over full rows (cols split across 16 waves) ----
    // C/D layout: col = l15, row-in-tile = 4*g + q
    float mrow[MT][4];
    #pragma unroll
    for (int r = 0; r < MT; ++r)
        #pragma unroll
        for (int q = 0; q < 4; ++q) {
            float m = acc[r][0][q];
            #pragma unroll
            for (int ct = 1; ct < NCT; ++ct) m = fmaxf(m, acc[r][ct][q]);
            #pragma unroll
            for (int s = 1; s < 16; s <<= 1) m = fmaxf(m, __shfl_xor(m, s, 64));
            mrow[r][q] = m;
        }
    if (l15 == 0) {
        #pragma unroll
        for (int r = 0; r < MT; ++r)
            #pragma unroll
            for (int q = 0; q < 4; ++q)
                redbuf[wid][r * 16 + g * 4 + q] = mrow[r][q];
    }
    __syncthreads();
    #pragma unroll
    for (int r = 0; r < MT; ++r)
        #pragma unroll
        for (int q = 0; q < 4; ++q) {
            int row = r * 16 + g * 4 + q;
            float m = redbuf[0][row];
            #pragma unroll
            for (int w = 1; w < NWAVES; ++w) m = fmaxf(m, redbuf[w][row]);
            mrow[r][q] = m;
        }
    __syncthreads();   // redbuf reused for sums

    #pragma unroll
    for (int r = 0; r < MT; ++r)
        #pragma unroll
        for (int q = 0; q < 4; ++q) {
            float s = 0.f;
            #pragma unroll
            for (int ct = 0; ct < NCT; ++ct) {
                float e = __expf(acc[r][ct][q] - mrow[r][q]);
                acc[r][ct][q] = e;
                s += e;
            }
            #pragma unroll
            for (int sh = 1; sh < 16; sh <<= 1) s += __shfl_xor(s, sh, 64);
            if (l15 == 0) redbuf[wid][r * 16 + g * 4 + q] = s;
        }
    __syncthreads();

    // ---- epilogue: P via LDS transpose, fully-coalesced global IO ----
    float* Pb = (float*)lds;            // [16][1024] f32 = 64 KiB (reuse slice mem)
    float* ob = out + (size_t)b * NN * NN;
    #pragma unroll
    for (int r = 0; r < MT; ++r) {
        __syncthreads();                // previous phase's gathers done
        #pragma unroll
        for (int q = 0; q < 4; ++q) {
            int row = r * 16 + g * 4 + q;
            float tot = redbuf[0][row];
            #pragma unroll
            for (int w = 1; w < NWAVES; ++w) tot += redbuf[w][row];
            float inv = 1.0f / tot;
            #pragma unroll
            for (int ct = 0; ct < NCT; ++ct)
                Pb[(g * 4 + q) * NN + (jb + ct * 16 + l15)] = acc[r][ct][q] * inv;
        }
        __syncthreads();                // P tile visible
        const int rowg   = i0 + r * 16 + wid;      // wave <-> row
        const float* xr  = xb + (size_t)rowg * NN;
        float*       orw = ob + (size_t)rowg * NN;
        const float* pr  = Pb + wid * NN;
        #pragma unroll
        for (int jj = 0; jj < 4; ++jj) {
            int cix = jj * 256 + lane * 4;
            float4 pv = *reinterpret_cast<const float4*>(pr + cix);
            float4 xv = *reinterpret_cast<const float4*>(xr + cix);
            float4 ov;
            ov.x = xv.x * pv.x; ov.y = xv.y * pv.y;
            ov.z = xv.z * pv.z; ov.w = xv.w * pv.w;
            *reinterpret_cast<float4*>(orw + cix) = ov;
        }
    }
}

// ---------- fallback (no usable workspace): round-2/3 proven fp32-direct ----------
#define FB_NWAVES 8
#define FB_NTHR   512
#define FB_NCT    8

static __device__ __forceinline__ short8 cvt8(float4 u0, float4 u1) {
    short8 r;
    r[0] = (short)cvt_bf16(u0.x); r[1] = (short)cvt_bf16(u0.y);
    r[2] = (short)cvt_bf16(u0.z); r[3] = (short)cvt_bf16(u0.w);
    r[4] = (short)cvt_bf16(u1.x); r[5] = (short)cvt_bf16(u1.y);
    r[6] = (short)cvt_bf16(u1.z); r[7] = (short)cvt_bf16(u1.w);
    return r;
}

__global__ __launch_bounds__(FB_NTHR, 2)
void attn_fb(const float* __restrict__ x, float* __restrict__ out) {
    const int wg   = blockIdx.x;
    const int t    = wg >> 3;
    const int b    = (wg & 7) + 8 * (t >> 4);
    const int i0   = (t & 15) * ROWS;
    const int tid  = threadIdx.x;
    const int lane = tid & 63;
    const int wid  = tid >> 6;
    const int l15  = lane & 15;
    const int g    = lane >> 4;

    const float* xb = x + (size_t)b * NN * NN;
    __shared__ unsigned short ldsA[ROWS * NN];
    __shared__ float redbuf[FB_NWAVES][ROWS];

    {
        const float* Ar = xb + (size_t)i0 * NN;
        #pragma unroll
        for (int it = 0; it < (ROWS * NN / 4) / FB_NTHR; ++it) {
            int f4  = tid + it * FB_NTHR;
            int row = f4 >> 8;
            int d   = (f4 & 255) << 2;
            float4 v = *reinterpret_cast<const float4*>(Ar + row * NN + d);
            int e = (row * NN + d) ^ ((row & 15) << 3);
            ushort4 h;
            h.x = cvt_bf16(v.x); h.y = cvt_bf16(v.y);
            h.z = cvt_bf16(v.z); h.w = cvt_bf16(v.w);
            *reinterpret_cast<ushort4*>(&ldsA[e]) = h;
        }
    }
    __syncthreads();

    f32x4 acc[MT][FB_NCT];
    #pragma unroll
    for (int r = 0; r < MT; ++r)
        #pragma unroll
        for (int ct = 0; ct < FB_NCT; ++ct)
            acc[r][ct] = (f32x4){0.f, 0.f, 0.f, 0.f};

    const int jb = wid * (FB_NCT * 16);
    const float* Bb = xb + (size_t)(jb + l15) * NN + g * 8;

    #pragma unroll 1
    for (int k = 0; k < NN; k += 32) {
        short8 ar[MT];
        #pragma unroll
        for (int r = 0; r < MT; ++r) {
            int e = ((r * 16 + l15) * NN + k + g * 8) ^ (l15 << 3);
            ar[r] = *reinterpret_cast<const short8*>(&ldsA[e]);
        }
        #pragma unroll
        for (int ct = 0; ct < FB_NCT; ++ct) {
            const float* p = Bb + ct * (16 * NN) + k;
            float4 u0 = *reinterpret_cast<const float4*>(p);
            float4 u1 = *reinterpret_cast<const float4*>(p + 4);
            short8 bf = cvt8(u0, u1);
            #pragma unroll
            for (int r = 0; r < MT; ++r)
                acc[r][ct] = __builtin_amdgcn_mfma_f32_16x16x32_bf16(
                    ar[r], bf, acc[r][ct], 0, 0, 0);
        }
    }

    float mrow[MT][4];
    #pragma unroll
    for (int r = 0; r < MT; ++r)
        #pragma unroll
        for (int q = 0; q < 4; ++q) {
            float m = acc[r][0][q];
            #pragma unroll
            for (int ct = 1; ct < FB_NCT; ++ct) m = fmaxf(m, acc[r][ct][q]);
            #pragma unroll
            for (int s = 1; s < 16; s <<= 1) m = fmaxf(m, __shfl_xor(m, s, 64));
            mrow[r][q] = m;
        }
    if (l15 == 0) {
        #pragma unroll
        for (int r = 0; r < MT; ++r)
            #pragma unroll
            for (int q = 0; q < 4; ++q)
                redbuf[wid][r * 16 + g * 4 + q] = mrow[r][q];
    }
    __syncthreads();
    #pragma unroll
    for (int r = 0; r < MT; ++r)
        #pragma unroll
        for (int q = 0; q < 4; ++q) {
            int row = r * 16 + g * 4 + q;
            float m = redbuf[0][row];
            #pragma unroll
            for (int w = 1; w < FB_NWAVES; ++w) m = fmaxf(m, redbuf[w][row]);
            mrow[r][q] = m;
        }
    __syncthreads();

    float srow[MT][4];
    #pragma unroll
    for (int r = 0; r < MT; ++r)
        #pragma unroll
        for (int q = 0; q < 4; ++q) {
            float s = 0.f;
            #pragma unroll
            for (int ct = 0; ct < FB_NCT; ++ct) {
                float e = __expf(acc[r][ct][q] - mrow[r][q]);
                acc[r][ct][q] = e;
                s += e;
            }
            #pragma unroll
            for (int sh = 1; sh < 16; sh <<= 1) s += __shfl_xor(s, sh, 64);
            srow[r][q] = s;
        }
    if (l15 == 0) {
        #pragma unroll
        for (int r = 0; r < MT; ++r)
            #pragma unroll
            for (int q = 0; q < 4; ++q)
                redbuf[wid][r * 16 + g * 4 + q] = srow[r][q];
    }
    __syncthreads();

    float* ob = out + (size_t)b * NN * NN;
    #pragma unroll
    for (int r = 0; r < MT; ++r)
        #pragma unroll
        for (int q = 0; q < 4; ++q) {
            int row = r * 16 + g * 4 + q;
            float tot = redbuf[0][row];
            #pragma unroll
            for (int w = 1; w < FB_NWAVES; ++w) tot += redbuf[w][row];
            float inv = 1.0f / tot;
            const size_t rowoff = (size_t)(i0 + row) * NN;
            #pragma unroll
            for (int ct = 0; ct < FB_NCT; ++ct) {
                int j_ = jb + ct * 16 + l15;
                ob[rowoff + j_] = xb[rowoff + j_] * acc[r][ct][q] * inv;
            }
        }
}

extern "C" void kernel_launch(void* const* d_in, const int* in_sizes, int n_in,
                              void* d_out, int out_size, void* d_ws, size_t ws_size,
                              hipStream_t stream) {
    const float* x = (const float*)d_in[0];
    float* out = (float*)d_out;
    const size_t need = (size_t)BATCH * NN * NN * sizeof(unsigned short);  // 32 MiB
    dim3 grid(BATCH * (NN / ROWS));   // 256 WGs, 1 per CU
    if (ws_size >= need) {
        unsigned short* xw = (unsigned short*)d_ws;
        cvt_kernel<<<2048, 256, 0, stream>>>(x, xw);
        attn_v4<<<grid, NTHR, 0, stream>>>(x, xw, out);
    } else {
        attn_fb<<<grid, FB_NTHR, 0, stream>>>(x, out);
    }
}

// Round 6
// 177.469 us; speedup vs baseline: 1.6487x; 1.6487x over previous
//
#include <hip/hip_runtime.h>
#include <hip/hip_bf16.h>

#define BATCH   16
#define NN      1024
#define ROWS    64      // score rows per workgroup
#define NWAVES  8
#define NTHR    512
#define BK      32      // K-slice per step
#define NSTEP   (NN / BK)
#define MT      4       // 16-row M tiles per wave
#define NCT     8       // 16-col tiles per wave -> 128 cols/wave
#define PLD     1028    // padded P-row stride (f32) -> epilogue bank spread

typedef __attribute__((ext_vector_type(8))) short short8;   // 8 x bf16
typedef __attribute__((ext_vector_type(4))) float f32x4;

static __device__ __forceinline__ unsigned short cvt_bf16(float f) {
    unsigned int u = __builtin_bit_cast(unsigned int, f);
    u += 0x7fffu + ((u >> 16) & 1u);
    return (unsigned short)(u >> 16);
}

// pre-pass: x (fp32) -> bf16 copy in workspace (halves L2-side BW demand)
__global__ __launch_bounds__(256)
void cvt_kernel(const float* __restrict__ x, unsigned short* __restrict__ xw) {
    const int n4 = BATCH * NN * NN / 4;
    int i = blockIdx.x * 256 + threadIdx.x;
    const int stride = gridDim.x * 256;
    for (; i < n4; i += stride) {
        float4 v = reinterpret_cast<const float4*>(x)[i];
        ushort4 h;
        h.x = cvt_bf16(v.x); h.y = cvt_bf16(v.y);
        h.z = cvt_bf16(v.z); h.w = cvt_bf16(v.w);
        reinterpret_cast<ushort4*>(xw)[i] = h;
    }
}

// stage one bf16 K-slice [1024 rows x BK] -> LDS buffer bb (coalesced,
// source-granule XOR-permuted; read side applies the same involution)
#define STAGE(bb, k0)                                                          \
    {                                                                          \
        _Pragma("unroll")                                                      \
        for (int c = 0; c < 8; ++c) {                                          \
            __builtin_amdgcn_global_load_lds(                                  \
                (const __attribute__((address_space(1))) void*)(xwb + soff[c] + (k0)), \
                (__attribute__((address_space(3))) void*)(lds + (bb) * 65536 + (wid * 8 + c) * 1024), \
                16, 0, 0);                                                     \
        }                                                                      \
    }

__global__ __launch_bounds__(NTHR, 2)
void attn_v5(const float* __restrict__ x, const unsigned short* __restrict__ xw,
             float* __restrict__ out) {
    // batch-contiguous XCD swizzle: XCD (wg&7) hosts batches {wg&7, (wg&7)+8}
    const int wg   = blockIdx.x;
    const int t_   = wg >> 3;
    const int b    = (wg & 7) + 8 * (t_ >> 4);
    const int i0   = (t_ & 15) * ROWS;
    const int tid  = threadIdx.x;
    const int lane = tid & 63;
    const int wid  = tid >> 6;
    const int l15  = lane & 15;   // M/N index within a 16-tile
    const int g    = lane >> 4;   // K-group / C-row group

    __shared__ __align__(16) unsigned char lds[131072];   // 2 x 64 KiB slices / P-buf
    __shared__ float redbuf[NWAVES][ROWS];                // 2 KiB

    const unsigned short* xwb = xw + (size_t)b * (NN * NN);
    const float* xb = x + (size_t)b * (NN * NN);

    // staging source offsets: LDS granule G = (wid*8+c)*64 + lane holds
    // global granule (row = G>>2, slot (lane&3) sourced from sg = slot ^ ((row>>1)&3))
    int soff[8];
    #pragma unroll
    for (int c = 0; c < 8; ++c) {
        int G   = (wid * 8 + c) * 64 + lane;
        int row = G >> 2;
        int sg  = (lane & 3) ^ ((row >> 1) & 3);
        soff[c] = row * NN + sg * 8;
    }

    f32x4 acc[MT][NCT];
    #pragma unroll
    for (int r = 0; r < MT; ++r)
        #pragma unroll
        for (int ct = 0; ct < NCT; ++ct)
            acc[r][ct] = (f32x4){0.f, 0.f, 0.f, 0.f};

    const int jb = wid * (NCT * 16);   // wave's col base (128 cols/wave)

    // ---- 2-phase double-buffered K-loop ----
    STAGE(0, 0)
    __syncthreads();

    #pragma unroll 1
    for (int t = 0; t < NSTEP; ++t) {
        if (t + 1 < NSTEP) STAGE((t + 1) & 1, (t + 1) * BK)

        const unsigned char* cur = lds + (t & 1) * 65536;
        short8 bfr[NCT];
        #pragma unroll
        for (int ct = 0; ct < NCT; ++ct) {
            int row = jb + ct * 16 + l15;
            int gr  = row * 4 + (g ^ ((row >> 1) & 3));
            bfr[ct] = *reinterpret_cast<const short8*>(cur + gr * 16);
        }

        __builtin_amdgcn_s_setprio(1);
        #pragma unroll
        for (int r = 0; r < MT; ++r) {
            int row = i0 + r * 16 + l15;               // A rows live in the slice too
            int gr  = row * 4 + (g ^ ((row >> 1) & 3));
            short8 a = *reinterpret_cast<const short8*>(cur + gr * 16);
            #pragma unroll
            for (int ct = 0; ct < NCT; ++ct)
                acc[r][ct] = __builtin_amdgcn_mfma_f32_16x16x32_bf16(
                    a, bfr[ct], acc[r][ct], 0, 0, 0);
        }
        __builtin_amdgcn_s_setprio(0);

        __syncthreads();   // drains vmcnt (stage) + lgkm; publishes next slice
    }

    // ---- softmax over full rows (cols split across 8 waves) ----
    // C/D layout: col = l15, row-in-tile = 4*g + q
    float mrow[MT][4];
    #pragma unroll
    for (int r = 0; r < MT; ++r)
        #pragma unroll
        for (int q = 0; q < 4; ++q) {
            float m = acc[r][0][q];
            #pragma unroll
            for (int ct = 1; ct < NCT; ++ct) m = fmaxf(m, acc[r][ct][q]);
            #pragma unroll
            for (int s = 1; s < 16; s <<= 1) m = fmaxf(m, __shfl_xor(m, s, 64));
            mrow[r][q] = m;
        }
    if (l15 == 0) {
        #pragma unroll
        for (int r = 0; r < MT; ++r)
            #pragma unroll
            for (int q = 0; q < 4; ++q)
                redbuf[wid][r * 16 + g * 4 + q] = mrow[r][q];
    }
    __syncthreads();
    #pragma unroll
    for (int r = 0; r < MT; ++r)
        #pragma unroll
        for (int q = 0; q < 4; ++q) {
            int row = r * 16 + g * 4 + q;
            float m = redbuf[0][row];
            #pragma unroll
            for (int w = 1; w < NWAVES; ++w) m = fmaxf(m, redbuf[w][row]);
            mrow[r][q] = m;
        }
    __syncthreads();   // redbuf reused for sums

    #pragma unroll
    for (int r = 0; r < MT; ++r)
        #pragma unroll
        for (int q = 0; q < 4; ++q) {
            float s = 0.f;
            #pragma unroll
            for (int ct = 0; ct < NCT; ++ct) {
                float e = __expf(acc[r][ct][q] - mrow[r][q]);
                acc[r][ct][q] = e;
                s += e;
            }
            #pragma unroll
            for (int sh = 1; sh < 16; sh <<= 1) s += __shfl_xor(s, sh, 64);
            if (l15 == 0) redbuf[wid][r * 16 + g * 4 + q] = s;
        }
    __syncthreads();

    // ---- epilogue: P via padded LDS transpose, fully-coalesced global IO ----
    float* Pb = (float*)lds;            // [16][PLD] f32 (reuses slice memory)
    float* ob = out + (size_t)b * NN * NN;
    #pragma unroll
    for (int r = 0; r < MT; ++r) {
        #pragma unroll
        for (int q = 0; q < 4; ++q) {
            int row = r * 16 + g * 4 + q;
            float tot = redbuf[0][row];
            #pragma unroll
            for (int w = 1; w < NWAVES; ++w) tot += redbuf[w][row];
            float inv = 1.0f / tot;
            #pragma unroll
            for (int ct = 0; ct < NCT; ++ct)
                Pb[(g * 4 + q) * PLD + (jb + ct * 16 + l15)] = acc[r][ct][q] * inv;
        }
        __syncthreads();                // P tile visible
        #pragma unroll
        for (int h = 0; h < 2; ++h) {
            const int rowl = wid + 8 * h;               // wave <-> 2 rows
            const int rowg = i0 + r * 16 + rowl;
            const float* xr  = xb + (size_t)rowg * NN;
            float*       orw = ob + (size_t)rowg * NN;
            const float* pr  = Pb + rowl * PLD;
            #pragma unroll
            for (int jj = 0; jj < 4; ++jj) {
                int cix = jj * 256 + lane * 4;
                float4 pv = *reinterpret_cast<const float4*>(pr + cix);
                float4 xv = *reinterpret_cast<const float4*>(xr + cix);
                float4 ov;
                ov.x = xv.x * pv.x; ov.y = xv.y * pv.y;
                ov.z = xv.z * pv.z; ov.w = xv.w * pv.w;
                *reinterpret_cast<float4*>(orw + cix) = ov;
            }
        }
        __syncthreads();                // before overwriting Pb next r
    }
}

// ---------- fallback (no usable workspace): round-2 proven fp32-direct ----------
#define FB_NWAVES 8
#define FB_NTHR   512
#define FB_NCT    8

static __device__ __forceinline__ short8 cvt8(float4 u0, float4 u1) {
    short8 r;
    r[0] = (short)cvt_bf16(u0.x); r[1] = (short)cvt_bf16(u0.y);
    r[2] = (short)cvt_bf16(u0.z); r[3] = (short)cvt_bf16(u0.w);
    r[4] = (short)cvt_bf16(u1.x); r[5] = (short)cvt_bf16(u1.y);
    r[6] = (short)cvt_bf16(u1.z); r[7] = (short)cvt_bf16(u1.w);
    return r;
}

__global__ __launch_bounds__(FB_NTHR, 2)
void attn_fb(const float* __restrict__ x, float* __restrict__ out) {
    const int wg   = blockIdx.x;
    const int t    = wg >> 3;
    const int b    = (wg & 7) + 8 * (t >> 4);
    const int i0   = (t & 15) * ROWS;
    const int tid  = threadIdx.x;
    const int lane = tid & 63;
    const int wid  = tid >> 6;
    const int l15  = lane & 15;
    const int g    = lane >> 4;

    const float* xb = x + (size_t)b * NN * NN;
    __shared__ unsigned short ldsA[ROWS * NN];
    __shared__ float redbuf[FB_NWAVES][ROWS];

    {
        const float* Ar = xb + (size_t)i0 * NN;
        #pragma unroll
        for (int it = 0; it < (ROWS * NN / 4) / FB_NTHR; ++it) {
            int f4  = tid + it * FB_NTHR;
            int row = f4 >> 8;
            int d   = (f4 & 255) << 2;
            float4 v = *reinterpret_cast<const float4*>(Ar + row * NN + d);
            int e = (row * NN + d) ^ ((row & 15) << 3);
            ushort4 h;
            h.x = cvt_bf16(v.x); h.y = cvt_bf16(v.y);
            h.z = cvt_bf16(v.z); h.w = cvt_bf16(v.w);
            *reinterpret_cast<ushort4*>(&ldsA[e]) = h;
        }
    }
    __syncthreads();

    f32x4 acc[MT][FB_NCT];
    #pragma unroll
    for (int r = 0; r < MT; ++r)
        #pragma unroll
        for (int ct = 0; ct < FB_NCT; ++ct)
            acc[r][ct] = (f32x4){0.f, 0.f, 0.f, 0.f};

    const int jb = wid * (FB_NCT * 16);
    const float* Bb = xb + (size_t)(jb + l15) * NN + g * 8;

    #pragma unroll 1
    for (int k = 0; k < NN; k += 32) {
        short8 ar[MT];
        #pragma unroll
        for (int r = 0; r < MT; ++r) {
            int e = ((r * 16 + l15) * NN + k + g * 8) ^ (l15 << 3);
            ar[r] = *reinterpret_cast<const short8*>(&ldsA[e]);
        }
        #pragma unroll
        for (int ct = 0; ct < FB_NCT; ++ct) {
            const float* p = Bb + ct * (16 * NN) + k;
            float4 u0 = *reinterpret_cast<const float4*>(p);
            float4 u1 = *reinterpret_cast<const float4*>(p + 4);
            short8 bf = cvt8(u0, u1);
            #pragma unroll
            for (int r = 0; r < MT; ++r)
                acc[r][ct] = __builtin_amdgcn_mfma_f32_16x16x32_bf16(
                    ar[r], bf, acc[r][ct], 0, 0, 0);
        }
    }

    float mrow[MT][4];
    #pragma unroll
    for (int r = 0; r < MT; ++r)
        #pragma unroll
        for (int q = 0; q < 4; ++q) {
            float m = acc[r][0][q];
            #pragma unroll
            for (int ct = 1; ct < FB_NCT; ++ct) m = fmaxf(m, acc[r][ct][q]);
            #pragma unroll
            for (int s = 1; s < 16; s <<= 1) m = fmaxf(m, __shfl_xor(m, s, 64));
            mrow[r][q] = m;
        }
    if (l15 == 0) {
        #pragma unroll
        for (int r = 0; r < MT; ++r)
            #pragma unroll
            for (int q = 0; q < 4; ++q)
                redbuf[wid][r * 16 + g * 4 + q] = mrow[r][q];
    }
    __syncthreads();
    #pragma unroll
    for (int r = 0; r < MT; ++r)
        #pragma unroll
        for (int q = 0; q < 4; ++q) {
            int row = r * 16 + g * 4 + q;
            float m = redbuf[0][row];
            #pragma unroll
            for (int w = 1; w < FB_NWAVES; ++w) m = fmaxf(m, redbuf[w][row]);
            mrow[r][q] = m;
        }
    __syncthreads();

    float srow[MT][4];
    #pragma unroll
    for (int r = 0; r < MT; ++r)
        #pragma unroll
        for (int q = 0; q < 4; ++q) {
            float s = 0.f;
            #pragma unroll
            for (int ct = 0; ct < FB_NCT; ++ct) {
                float e = __expf(acc[r][ct][q] - mrow[r][q]);
                acc[r][ct][q] = e;
                s += e;
            }
            #pragma unroll
            for (int sh = 1; sh < 16; sh <<= 1) s += __shfl_xor(s, sh, 64);
            srow[r][q] = s;
        }
    if (l15 == 0) {
        #pragma unroll
        for (int r = 0; r < MT; ++r)
            #pragma unroll
            for (int q = 0; q < 4; ++q)
                redbuf[wid][r * 16 + g * 4 + q] = srow[r][q];
    }
    __syncthreads();

    float* ob = out + (size_t)b * NN * NN;
    #pragma unroll
    for (int r = 0; r < MT; ++r)
        #pragma unroll
        for (int q = 0; q < 4; ++q) {
            int row = r * 16 + g * 4 + q;
            float tot = redbuf[0][row];
            #pragma unroll
            for (int w = 1; w < FB_NWAVES; ++w) tot += redbuf[w][row];
            float inv = 1.0f / tot;
            const size_t rowoff = (size_t)(i0 + row) * NN;
            #pragma unroll
            for (int ct = 0; ct < FB_NCT; ++ct) {
                int j_ = jb + ct * 16 + l15;
                ob[rowoff + j_] = xb[rowoff + j_] * acc[r][ct][q] * inv;
            }
        }
}

extern "C" void kernel_launch(void* const* d_in, const int* in_sizes, int n_in,
                              void* d_out, int out_size, void* d_ws, size_t ws_size,
                              hipStream_t stream) {
    const float* x = (const float*)d_in[0];
    float* out = (float*)d_out;
    const size_t need = (size_t)BATCH * NN * NN * sizeof(unsigned short);  // 32 MiB
    dim3 grid(BATCH * (NN / ROWS));   // 256 WGs, 1 per CU
    if (ws_size >= need) {
        unsigned short* xw = (unsigned short*)d_ws;
        cvt_kernel<<<2048, 256, 0, stream>>>(x, xw);
        attn_v5<<<grid, NTHR, 0, stream>>>(x, xw, out);
    } else {
        attn_fb<<<grid, FB_NTHR, 0, stream>>>(x, out);
    }
}